// Round 1
// baseline (538.725 us; speedup 1.0000x reference)
//
#include <hip/hip_runtime.h>

#define LQ 1024
#define DMODEL 1024
#define NHEAD 16
#define HDIM 64

// ============================ RMSNorm =====================================
// row 0..1023 -> x (writes xqn = rms(x)*gq, xkvn = rms(x)*gkv)
// row 1024..2047 -> pt (writes ptn = rms(pt)*gc)
__global__ __launch_bounds__(256) void rms_kernel(
    const float* __restrict__ x, const float* __restrict__ pt,
    const float* __restrict__ gq, const float* __restrict__ gkv,
    const float* __restrict__ gc,
    float* __restrict__ xqn, float* __restrict__ xkvn, float* __restrict__ ptn)
{
    const int row = blockIdx.x;
    const int t = threadIdx.x;
    const bool isx = row < LQ;
    const float* src = isx ? (x + (size_t)row * DMODEL)
                           : (pt + (size_t)(row - LQ) * DMODEL);
    float4 v = ((const float4*)src)[t];
    float ss = v.x*v.x + v.y*v.y + v.z*v.z + v.w*v.w;
    #pragma unroll
    for (int o = 32; o > 0; o >>= 1) ss += __shfl_down(ss, o);
    __shared__ float red[4];
    if ((t & 63) == 0) red[t >> 6] = ss;
    __syncthreads();
    const float r = rsqrtf((red[0] + red[1] + red[2] + red[3]) * (1.0f / DMODEL)
                           + 1.1920929e-07f);
    if (isx) {
        float4 g1 = ((const float4*)gq)[t];
        float4 g2 = ((const float4*)gkv)[t];
        float4 o1, o2;
        o1.x = v.x*r*g1.x; o1.y = v.y*r*g1.y; o1.z = v.z*r*g1.z; o1.w = v.w*r*g1.w;
        o2.x = v.x*r*g2.x; o2.y = v.y*r*g2.y; o2.z = v.z*r*g2.z; o2.w = v.w*r*g2.w;
        ((float4*)(xqn + (size_t)row * DMODEL))[t] = o1;
        ((float4*)(xkvn + (size_t)row * DMODEL))[t] = o2;
    } else {
        float4 g = ((const float4*)gc)[t];
        float4 o1;
        o1.x = v.x*r*g.x; o1.y = v.y*r*g.y; o1.z = v.z*r*g.z; o1.w = v.w*r*g.w;
        ((float4*)(ptn + (size_t)(row - LQ) * DMODEL))[t] = o1;
    }
}

// ====================== fp32 GEMM tile (128x64, 8x4 micro) ================
// out[M=1024 x N] = A[1024 x 1024] @ W[1024 x N] + bias
__device__ __forceinline__ void gemm_tile(
    const float* __restrict__ A, const float* __restrict__ W,
    const float* __restrict__ bias, float* __restrict__ out,
    int N, int mt, int nt)
{
    __shared__ float As[8][128];   // [k][m]
    __shared__ float Bs[8][64];    // [k][n]
    const int t = threadIdx.x;
    const int tx = t & 15;         // n micro (4 cols)
    const int ty = t >> 4;         // m micro (8 rows)
    const int arow = t >> 1;             // 0..127
    const int acol = (t & 1) * 4;        // 0 or 4
    float acc[8][4];
    #pragma unroll
    for (int i = 0; i < 8; ++i)
        #pragma unroll
        for (int j = 0; j < 4; ++j) acc[i][j] = 0.f;

    for (int kt = 0; kt < 128; ++kt) {
        float4 av = *(const float4*)(A + (size_t)(mt * 128 + arow) * 1024 + kt * 8 + acol);
        float4 bv;
        if (t < 128)
            bv = *(const float4*)(W + (size_t)(kt * 8 + (t >> 4)) * N + nt * 64 + (t & 15) * 4);
        __syncthreads();
        As[acol + 0][arow] = av.x;
        As[acol + 1][arow] = av.y;
        As[acol + 2][arow] = av.z;
        As[acol + 3][arow] = av.w;
        if (t < 128) *(float4*)&Bs[t >> 4][(t & 15) * 4] = bv;
        __syncthreads();
        #pragma unroll
        for (int kk = 0; kk < 8; ++kk) {
            float4 a0 = *(const float4*)&As[kk][ty * 8];
            float4 a1 = *(const float4*)&As[kk][ty * 8 + 4];
            float4 b0 = *(const float4*)&Bs[kk][tx * 4];
            float aa[8] = {a0.x, a0.y, a0.z, a0.w, a1.x, a1.y, a1.z, a1.w};
            float bb[4] = {b0.x, b0.y, b0.z, b0.w};
            #pragma unroll
            for (int i = 0; i < 8; ++i)
                #pragma unroll
                for (int j = 0; j < 4; ++j)
                    acc[i][j] = fmaf(aa[i], bb[j], acc[i][j]);
        }
    }
    float4 bb = *(const float4*)(bias + nt * 64 + tx * 4);
    #pragma unroll
    for (int i = 0; i < 8; ++i) {
        int row = mt * 128 + ty * 8 + i;
        float4 o;
        o.x = acc[i][0] + bb.x; o.y = acc[i][1] + bb.y;
        o.z = acc[i][2] + bb.z; o.w = acc[i][3] + bb.w;
        *(float4*)(out + (size_t)row * N + nt * 64 + tx * 4) = o;
    }
}

// 3 projections fused in one launch: Q(128 blocks) | KV(256) | C(128)
__global__ __launch_bounds__(256) void proj_kernel(
    const float* __restrict__ xqn, const float* __restrict__ xkvn,
    const float* __restrict__ ptn,
    const float* __restrict__ Wq, const float* __restrict__ bq,
    const float* __restrict__ Wkv, const float* __restrict__ bkv,
    const float* __restrict__ Wc, const float* __restrict__ bc,
    float* __restrict__ Qb, float* __restrict__ KVb, float* __restrict__ Cb)
{
    const int bid = blockIdx.x;
    if (bid < 128) {
        gemm_tile(xqn, Wq, bq, Qb, 1024, bid >> 4, bid & 15);
    } else if (bid < 384) {
        int b2 = bid - 128;
        gemm_tile(xkvn, Wkv, bkv, KVb, 2048, b2 >> 5, b2 & 31);
    } else {
        int b2 = bid - 384;
        gemm_tile(ptn, Wc, bc, Cb, 1024, b2 >> 4, b2 & 15);
    }
}

__global__ __launch_bounds__(256) void gemm_kernel(
    const float* __restrict__ A, const float* __restrict__ W,
    const float* __restrict__ bias, float* __restrict__ out, int N)
{
    gemm_tile(A, W, bias, out, N, blockIdx.y, blockIdx.x);
}

// ===================== prefix sums of C over rows (per column) ============
__global__ __launch_bounds__(256) void csum_kernel(const float* __restrict__ Cb,
                                                   float* __restrict__ csum)
{
    const int cid = blockIdx.x >> 2;                       // 0..7 (chunk of 128 rows)
    const int col = ((blockIdx.x & 3) << 8) + threadIdx.x; // 0..1023
    const float* p = Cb + (size_t)cid * 128 * 1024 + col;
    float s = 0.f;
    #pragma unroll 8
    for (int r = 0; r < 128; ++r) s += p[(size_t)r * 1024];
    csum[cid * 1024 + col] = s;
}

// P[t][col] = sum_{u<t} C[u][col], t = 0..1024 (1025 rows)
__global__ __launch_bounds__(256) void scanp_kernel(const float* __restrict__ Cb,
                                                    const float* __restrict__ csum,
                                                    float* __restrict__ Pb)
{
    const int cid = blockIdx.x >> 2;
    const int col = ((blockIdx.x & 3) << 8) + threadIdx.x;
    float run = 0.f;
    for (int c = 0; c < cid; ++c) run += csum[c * 1024 + col];
    const float* p = Cb + (size_t)cid * 128 * 1024 + col;
    float* q = Pb + (size_t)cid * 128 * 1024 + col;
    for (int r = 0; r < 128; ++r) {
        q[(size_t)r * 1024] = run;
        run += p[(size_t)r * 1024];
    }
    if (cid == 7) Pb[(size_t)1024 * 1024 + col] = run;
}

// ============== build A = [q, q*PE], B = [k*(scale-PS), k] per head =======
__global__ __launch_bounds__(256) void ab_kernel(
    const float* __restrict__ Qb, const float* __restrict__ KVb,
    const float* __restrict__ Pb, const int* __restrict__ cwp,
    float* __restrict__ Ab, float* __restrict__ Bb)
{
    const int gid = blockIdx.x * 256 + threadIdx.x;  // 0..1M-1
    const int i = gid >> 10;
    const int col = gid & 1023;
    const int h = col >> 6, dd = col & 63;
    const int cw = *cwp;
    const int E = min(i + cw, LQ);
    const int S = max(i - cw, 0);
    const float pe = Pb[(size_t)E * 1024 + col];
    const float ps = Pb[(size_t)S * 1024 + col];
    const float q = Qb[gid];
    const float k = KVb[(size_t)i * 2048 + col];
    const float scale = 0.125f;  // 64^-0.5
    float* ap = Ab + ((size_t)(h * 1024 + i)) * 128;
    ap[dd] = q;
    ap[64 + dd] = q * pe;
    float* bp = Bb + ((size_t)(h * 1024 + i)) * 128;
    bp[dd] = k * (scale - ps);
    bp[64 + dd] = k;
}

// ===================== flash attention (causal, 64x64 tiles) ==============
__global__ __launch_bounds__(256) void attn_kernel(
    const float* __restrict__ Ab, const float* __restrict__ Bb,
    const float* __restrict__ KVb, float* __restrict__ wv)
{
    __shared__ float As[128 * 64];   // [k][i] 32KB (lives whole kernel)
    __shared__ float Bs[128 * 64];   // [k][j] 32KB; reused as P(16KB)+V(16KB)
    float* Ps = Bs;                  // [j][i] 64x64
    float* Vs = Bs + 64 * 64;        // [j][dd] 64x64

    const int t = threadIdx.x;
    const int h = blockIdx.x >> 4;
    const int ib = blockIdx.x & 15;
    const int i0 = ib * 64;
    const int tx = t & 15;   // 4 j / 4 dd cols
    const int ty = t >> 4;   // 4 i rows

    {   // stage A tile transposed: As[k*64 + i]
        const int il = t >> 2, kq = (t & 3) * 32;
        const float* src = Ab + ((size_t)(h * 1024 + i0 + il)) * 128 + kq;
        #pragma unroll
        for (int u = 0; u < 8; ++u) {
            float4 v = *(const float4*)(src + u * 4);
            As[(kq + u * 4 + 0) * 64 + il] = v.x;
            As[(kq + u * 4 + 1) * 64 + il] = v.y;
            As[(kq + u * 4 + 2) * 64 + il] = v.z;
            As[(kq + u * 4 + 3) * 64 + il] = v.w;
        }
    }

    float m[4], l[4], o[4][4];
    #pragma unroll
    for (int r = 0; r < 4; ++r) {
        m[r] = -1e30f; l[r] = 0.f;
        #pragma unroll
        for (int c = 0; c < 4; ++c) o[r][c] = 0.f;
    }

    for (int jt = 0; jt <= ib; ++jt) {
        const int j0 = jt * 64;
        __syncthreads();  // prev iter done with Ps/Vs; A-stage complete (iter 0)
        {   // stage B tile transposed: Bs[k*64 + j]
            const int jl = t >> 2, kq = (t & 3) * 32;
            const float* src = Bb + ((size_t)(h * 1024 + j0 + jl)) * 128 + kq;
            #pragma unroll
            for (int u = 0; u < 8; ++u) {
                float4 v = *(const float4*)(src + u * 4);
                Bs[(kq + u * 4 + 0) * 64 + jl] = v.x;
                Bs[(kq + u * 4 + 1) * 64 + jl] = v.y;
                Bs[(kq + u * 4 + 2) * 64 + jl] = v.z;
                Bs[(kq + u * 4 + 3) * 64 + jl] = v.w;
            }
        }
        __syncthreads();

        float s[4][4];
        #pragma unroll
        for (int r = 0; r < 4; ++r) { s[r][0]=0.f; s[r][1]=0.f; s[r][2]=0.f; s[r][3]=0.f; }
        #pragma unroll 2
        for (int k = 0; k < 128; ++k) {
            float4 av = *(const float4*)&As[k * 64 + ty * 4];
            float4 bv = *(const float4*)&Bs[k * 64 + tx * 4];
            float aa[4] = {av.x, av.y, av.z, av.w};
            float bb[4] = {bv.x, bv.y, bv.z, bv.w};
            #pragma unroll
            for (int r = 0; r < 4; ++r)
                #pragma unroll
                for (int c = 0; c < 4; ++c)
                    s[r][c] = fmaf(aa[r], bb[c], s[r][c]);
        }
        if (jt == ib) {  // causal mask (finite to avoid NaN in online update)
            #pragma unroll
            for (int r = 0; r < 4; ++r)
                #pragma unroll
                for (int c = 0; c < 4; ++c)
                    if (j0 + tx * 4 + c > i0 + ty * 4 + r) s[r][c] = -1e30f;
        }

        float alpha[4];
        #pragma unroll
        for (int r = 0; r < 4; ++r) {
            float mt_ = fmaxf(fmaxf(s[r][0], s[r][1]), fmaxf(s[r][2], s[r][3]));
            mt_ = fmaxf(mt_, __shfl_xor(mt_, 1));
            mt_ = fmaxf(mt_, __shfl_xor(mt_, 2));
            mt_ = fmaxf(mt_, __shfl_xor(mt_, 4));
            mt_ = fmaxf(mt_, __shfl_xor(mt_, 8));
            const float mn = fmaxf(m[r], mt_);
            alpha[r] = __expf(m[r] - mn);
            m[r] = mn;
            float rs = 0.f;
            #pragma unroll
            for (int c = 0; c < 4; ++c) {
                float p = __expf(s[r][c] - mn);
                s[r][c] = p;
                rs += p;
            }
            rs += __shfl_xor(rs, 1); rs += __shfl_xor(rs, 2);
            rs += __shfl_xor(rs, 4); rs += __shfl_xor(rs, 8);
            l[r] = l[r] * alpha[r] + rs;
        }

        __syncthreads();  // everyone done reading Bs (S phase)
        #pragma unroll
        for (int c = 0; c < 4; ++c) {
            float4 pv;
            pv.x = s[0][c]; pv.y = s[1][c]; pv.z = s[2][c]; pv.w = s[3][c];
            *(float4*)&Ps[(tx * 4 + c) * 64 + ty * 4] = pv;   // [j][i]
        }
        {   // stage V: Vs[j*64 + dd]
            const int jl = t >> 2, du = (t & 3) * 16;
            const float* src = KVb + (size_t)(j0 + jl) * 2048 + 1024 + h * 64 + du;
            #pragma unroll
            for (int u = 0; u < 4; ++u)
                *(float4*)&Vs[jl * 64 + du + u * 4] = *(const float4*)(src + u * 4);
        }
        __syncthreads();

        #pragma unroll
        for (int r = 0; r < 4; ++r)
            #pragma unroll
            for (int c = 0; c < 4; ++c) o[r][c] *= alpha[r];
        #pragma unroll 2
        for (int k = 0; k < 64; ++k) {
            float4 pv = *(const float4*)&Ps[k * 64 + ty * 4];
            float4 vv = *(const float4*)&Vs[k * 64 + tx * 4];
            float pp[4] = {pv.x, pv.y, pv.z, pv.w};
            float vc[4] = {vv.x, vv.y, vv.z, vv.w};
            #pragma unroll
            for (int r = 0; r < 4; ++r)
                #pragma unroll
                for (int c = 0; c < 4; ++c)
                    o[r][c] = fmaf(pp[r], vc[c], o[r][c]);
        }
    }

    #pragma unroll
    for (int r = 0; r < 4; ++r) {
        const float inv = 1.0f / l[r];
        float4 ov;
        ov.x = o[r][0] * inv; ov.y = o[r][1] * inv;
        ov.z = o[r][2] * inv; ov.w = o[r][3] * inv;
        *(float4*)(wv + (size_t)(i0 + ty * 4 + r) * 1024 + h * 64 + tx * 4) = ov;
    }
}

// ================================ launch ==================================
extern "C" void kernel_launch(void* const* d_in, const int* in_sizes, int n_in,
                              void* d_out, int out_size, void* d_ws, size_t ws_size,
                              hipStream_t stream) {
    (void)in_sizes; (void)n_in; (void)out_size; (void)ws_size;
    const float* x    = (const float*)d_in[0];
    const float* pt   = (const float*)d_in[1];
    // d_in[2] = mask (unused: causal applied analytically; exp(-1e9) == 0 in fp32)
    const float* gq   = (const float*)d_in[3];
    const float* Wq   = (const float*)d_in[4];
    const float* bq   = (const float*)d_in[5];
    const float* gkv  = (const float*)d_in[6];
    const float* Wkv  = (const float*)d_in[7];
    const float* bkv  = (const float*)d_in[8];
    const float* gc   = (const float*)d_in[9];
    const float* Wc   = (const float*)d_in[10];
    const float* bc   = (const float*)d_in[11];
    const float* Wout = (const float*)d_in[12];
    const float* bout = (const float*)d_in[13];
    const int*   cw   = (const int*)d_in[14];
    float* out = (float*)d_out;

    const size_t M1 = 1u << 20;
    float* ws   = (float*)d_ws;
    float* xqn  = ws;
    float* xkvn = ws + 1 * M1;
    float* ptn  = ws + 2 * M1;
    float* Qb   = ws + 3 * M1;
    float* KVb  = ws + 4 * M1;   // 2M
    float* Cb   = ws + 6 * M1;
    float* Pb   = ws + 7 * M1;   // 1025*1024
    float* Ab   = ws + 9 * M1;   // 2M
    float* Bb   = ws + 11 * M1;  // 2M
    float* wvb  = ws + 13 * M1;
    float* csum = ws + 14 * M1;  // 8K

    hipLaunchKernelGGL(rms_kernel, dim3(2048), dim3(256), 0, stream,
                       x, pt, gq, gkv, gc, xqn, xkvn, ptn);
    hipLaunchKernelGGL(proj_kernel, dim3(512), dim3(256), 0, stream,
                       xqn, xkvn, ptn, Wq, bq, Wkv, bkv, Wc, bc, Qb, KVb, Cb);
    hipLaunchKernelGGL(csum_kernel, dim3(32), dim3(256), 0, stream, Cb, csum);
    hipLaunchKernelGGL(scanp_kernel, dim3(32), dim3(256), 0, stream, Cb, csum, Pb);
    hipLaunchKernelGGL(ab_kernel, dim3(4096), dim3(256), 0, stream,
                       Qb, KVb, Pb, cw, Ab, Bb);
    hipLaunchKernelGGL(attn_kernel, dim3(256), dim3(256), 0, stream,
                       Ab, Bb, KVb, wvb);
    hipLaunchKernelGGL(gemm_kernel, dim3(16, 8), dim3(256), 0, stream,
                       wvb, Wout, bout, out, 1024);
}

// Round 2
// 492.075 us; speedup vs baseline: 1.0948x; 1.0948x over previous
//
#include <hip/hip_runtime.h>

#define LQ 1024
#define DM 1024
#define NH 16
#define HD 64

// ============================ RMSNorm =====================================
__global__ __launch_bounds__(256) void rms_kernel(
    const float* __restrict__ x, const float* __restrict__ pt,
    const float* __restrict__ gq, const float* __restrict__ gkv,
    const float* __restrict__ gc,
    float* __restrict__ xqn, float* __restrict__ xkvn, float* __restrict__ ptn)
{
    const int row = blockIdx.x;
    const int t = threadIdx.x;
    const bool isx = row < LQ;
    const float* src = isx ? (x + (size_t)row * DM)
                           : (pt + (size_t)(row - LQ) * DM);
    float4 v = ((const float4*)src)[t];
    float ss = v.x*v.x + v.y*v.y + v.z*v.z + v.w*v.w;
    #pragma unroll
    for (int o = 32; o > 0; o >>= 1) ss += __shfl_down(ss, o);
    __shared__ float red[4];
    if ((t & 63) == 0) red[t >> 6] = ss;
    __syncthreads();
    const float r = rsqrtf((red[0] + red[1] + red[2] + red[3]) * (1.0f / DM)
                           + 1.1920929e-07f);
    if (isx) {
        float4 g1 = ((const float4*)gq)[t];
        float4 g2 = ((const float4*)gkv)[t];
        float4 o1, o2;
        o1.x = v.x*r*g1.x; o1.y = v.y*r*g1.y; o1.z = v.z*r*g1.z; o1.w = v.w*r*g1.w;
        o2.x = v.x*r*g2.x; o2.y = v.y*r*g2.y; o2.z = v.z*r*g2.z; o2.w = v.w*r*g2.w;
        ((float4*)(xqn + (size_t)row * DM))[t] = o1;
        ((float4*)(xkvn + (size_t)row * DM))[t] = o2;
    } else {
        float4 g = ((const float4*)gc)[t];
        float4 o1;
        o1.x = v.x*r*g.x; o1.y = v.y*r*g.y; o1.z = v.z*r*g.z; o1.w = v.w*r*g.w;
        ((float4*)(ptn + (size_t)(row - LQ) * DM))[t] = o1;
    }
}

// ============ generic 64x64 tiled transpose: out[C x R] = in[R x C]^T =====
__global__ __launch_bounds__(256) void transp_kernel(
    const float* __restrict__ in, float* __restrict__ out, int R, int C)
{
    __shared__ float T[64 * 65];
    const int t = threadIdx.x;
    const int tx = t & 15, ty = t >> 4;
    const int c0 = blockIdx.x * 64, r0 = blockIdx.y * 64;
    #pragma unroll
    for (int p = 0; p < 4; ++p) {
        int row = ty + p * 16;
        float4 v = *(const float4*)(in + (size_t)(r0 + row) * C + c0 + tx * 4);
        T[row * 65 + tx * 4 + 0] = v.x;
        T[row * 65 + tx * 4 + 1] = v.y;
        T[row * 65 + tx * 4 + 2] = v.z;
        T[row * 65 + tx * 4 + 3] = v.w;
    }
    __syncthreads();
    #pragma unroll
    for (int p = 0; p < 4; ++p) {
        int jl = ty + p * 16;
        float4 w;
        w.x = T[(tx * 4 + 0) * 65 + jl];
        w.y = T[(tx * 4 + 1) * 65 + jl];
        w.z = T[(tx * 4 + 2) * 65 + jl];
        w.w = T[(tx * 4 + 3) * 65 + jl];
        *(float4*)(out + (size_t)(c0 + jl) * R + r0 + tx * 4) = w;
    }
}

// ========= proj GEMM: 128x64 tile, 128 thr, 8x8 micro, K-slice 16 =========
// AT is A transposed: [K=1024][M=1024]. out[M x N] = A @ W + bias.
__device__ __forceinline__ void gemm128x64(
    const float* __restrict__ AT, const float* __restrict__ W,
    const float* __restrict__ bias, float* __restrict__ out,
    int N, int mt, int nt)
{
    __shared__ float As[16 * 128];   // [kk][i]
    __shared__ float Bs[16 * 64];    // [kk][j]
    const int t = threadIdx.x;
    const int tx = t & 7, ty = t >> 3;        // micro: 8 cols x 8 rows
    const int ks = t >> 4, lf = (t & 15) * 4; // staging coords
    float acc[8][8];
    #pragma unroll
    for (int i = 0; i < 8; ++i)
        #pragma unroll
        for (int j = 0; j < 8; ++j) acc[i][j] = 0.f;

    for (int kt = 0; kt < 64; ++kt) {
        const float* ab = AT + (size_t)(kt * 16 + ks) * 1024 + mt * 128;
        float4 a0 = *(const float4*)(ab + lf);
        float4 a1 = *(const float4*)(ab + lf + 64);
        float4 a2 = *(const float4*)(ab + (size_t)8 * 1024 + lf);
        float4 a3 = *(const float4*)(ab + (size_t)8 * 1024 + lf + 64);
        const float* bb = W + (size_t)(kt * 16 + ks) * N + nt * 64;
        float4 b0 = *(const float4*)(bb + lf);
        float4 b1 = *(const float4*)(bb + (size_t)8 * N + lf);
        __syncthreads();
        *(float4*)&As[ks * 128 + lf]            = a0;
        *(float4*)&As[ks * 128 + lf + 64]       = a1;
        *(float4*)&As[(ks + 8) * 128 + lf]      = a2;
        *(float4*)&As[(ks + 8) * 128 + lf + 64] = a3;
        *(float4*)&Bs[ks * 64 + lf]             = b0;
        *(float4*)&Bs[(ks + 8) * 64 + lf]       = b1;
        __syncthreads();
        #pragma unroll
        for (int kk = 0; kk < 16; ++kk) {
            float4 x0 = *(const float4*)&As[kk * 128 + ty * 8];
            float4 x1 = *(const float4*)&As[kk * 128 + ty * 8 + 4];
            float4 y0 = *(const float4*)&Bs[kk * 64 + tx * 8];
            float4 y1 = *(const float4*)&Bs[kk * 64 + tx * 8 + 4];
            float aa[8] = {x0.x, x0.y, x0.z, x0.w, x1.x, x1.y, x1.z, x1.w};
            float bbv[8] = {y0.x, y0.y, y0.z, y0.w, y1.x, y1.y, y1.z, y1.w};
            #pragma unroll
            for (int i = 0; i < 8; ++i)
                #pragma unroll
                for (int j = 0; j < 8; ++j)
                    acc[i][j] = fmaf(aa[i], bbv[j], acc[i][j]);
        }
    }
    float4 c0 = *(const float4*)(bias + nt * 64 + tx * 8);
    float4 c1 = *(const float4*)(bias + nt * 64 + tx * 8 + 4);
    float bv[8] = {c0.x, c0.y, c0.z, c0.w, c1.x, c1.y, c1.z, c1.w};
    #pragma unroll
    for (int i = 0; i < 8; ++i) {
        float* op = out + (size_t)(mt * 128 + ty * 8 + i) * N + nt * 64 + tx * 8;
        float4 o0, o1;
        o0.x = acc[i][0] + bv[0]; o0.y = acc[i][1] + bv[1];
        o0.z = acc[i][2] + bv[2]; o0.w = acc[i][3] + bv[3];
        o1.x = acc[i][4] + bv[4]; o1.y = acc[i][5] + bv[5];
        o1.z = acc[i][6] + bv[6]; o1.w = acc[i][7] + bv[7];
        *(float4*)op = o0;
        *(float4*)(op + 4) = o1;
    }
}

// Q(128 blocks) | KV(256) | C(128)
__global__ __launch_bounds__(128) void proj_kernel(
    const float* __restrict__ xqnT, const float* __restrict__ xkvnT,
    const float* __restrict__ ptnT,
    const float* __restrict__ Wq, const float* __restrict__ bq,
    const float* __restrict__ Wkv, const float* __restrict__ bkv,
    const float* __restrict__ Wc, const float* __restrict__ bc,
    float* __restrict__ Qb, float* __restrict__ KVb, float* __restrict__ Cb)
{
    const int bid = blockIdx.x;
    if (bid < 128) {
        gemm128x64(xqnT, Wq, bq, Qb, 1024, bid >> 4, bid & 15);
    } else if (bid < 384) {
        int b2 = bid - 128;
        gemm128x64(xkvnT, Wkv, bkv, KVb, 2048, b2 >> 5, b2 & 31);
    } else {
        int b2 = bid - 384;
        gemm128x64(ptnT, Wc, bc, Cb, 1024, b2 >> 4, b2 & 15);
    }
}

// ======= out GEMM: 64x64 tile, 128 thr, 4x8 micro, K-slice 16 =============
__global__ __launch_bounds__(128) void outgemm_kernel(
    const float* __restrict__ AT, const float* __restrict__ W,
    const float* __restrict__ bias, float* __restrict__ out)
{
    __shared__ float As[16 * 64];
    __shared__ float Bs[16 * 64];
    const int t = threadIdx.x;
    const int tx = t & 7, ty = t >> 3;        // 8 col-groups x 16 row-groups
    const int ks = t >> 4, lf = (t & 15) * 4;
    const int mt = blockIdx.y, nt = blockIdx.x;
    float acc[4][8];
    #pragma unroll
    for (int i = 0; i < 4; ++i)
        #pragma unroll
        for (int j = 0; j < 8; ++j) acc[i][j] = 0.f;

    for (int kt = 0; kt < 64; ++kt) {
        float4 a0 = *(const float4*)(AT + (size_t)(kt * 16 + ks) * 1024 + mt * 64 + lf);
        float4 a1 = *(const float4*)(AT + (size_t)(kt * 16 + ks + 8) * 1024 + mt * 64 + lf);
        float4 b0 = *(const float4*)(W + (size_t)(kt * 16 + ks) * 1024 + nt * 64 + lf);
        float4 b1 = *(const float4*)(W + (size_t)(kt * 16 + ks + 8) * 1024 + nt * 64 + lf);
        __syncthreads();
        *(float4*)&As[ks * 64 + lf]       = a0;
        *(float4*)&As[(ks + 8) * 64 + lf] = a1;
        *(float4*)&Bs[ks * 64 + lf]       = b0;
        *(float4*)&Bs[(ks + 8) * 64 + lf] = b1;
        __syncthreads();
        #pragma unroll
        for (int kk = 0; kk < 16; ++kk) {
            float4 x = *(const float4*)&As[kk * 64 + ty * 4];
            float4 y0 = *(const float4*)&Bs[kk * 64 + tx * 8];
            float4 y1 = *(const float4*)&Bs[kk * 64 + tx * 8 + 4];
            float aa[4] = {x.x, x.y, x.z, x.w};
            float bbv[8] = {y0.x, y0.y, y0.z, y0.w, y1.x, y1.y, y1.z, y1.w};
            #pragma unroll
            for (int i = 0; i < 4; ++i)
                #pragma unroll
                for (int j = 0; j < 8; ++j)
                    acc[i][j] = fmaf(aa[i], bbv[j], acc[i][j]);
        }
    }
    float4 c0 = *(const float4*)(bias + nt * 64 + tx * 8);
    float4 c1 = *(const float4*)(bias + nt * 64 + tx * 8 + 4);
    float bv[8] = {c0.x, c0.y, c0.z, c0.w, c1.x, c1.y, c1.z, c1.w};
    #pragma unroll
    for (int i = 0; i < 4; ++i) {
        float* op = out + (size_t)(mt * 64 + ty * 4 + i) * 1024 + nt * 64 + tx * 8;
        float4 o0, o1;
        o0.x = acc[i][0] + bv[0]; o0.y = acc[i][1] + bv[1];
        o0.z = acc[i][2] + bv[2]; o0.w = acc[i][3] + bv[3];
        o1.x = acc[i][4] + bv[4]; o1.y = acc[i][5] + bv[5];
        o1.z = acc[i][6] + bv[6]; o1.w = acc[i][7] + bv[7];
        *(float4*)op = o0;
        *(float4*)(op + 4) = o1;
    }
}

// ================== prefix sums of C over rows (32-row chunks) ============
__global__ __launch_bounds__(256) void csum_kernel(const float* __restrict__ Cb,
                                                   float* __restrict__ csum)
{
    const int cid = blockIdx.x >> 2;                       // 0..31
    const int col = ((blockIdx.x & 3) << 8) + threadIdx.x;
    const float* p = Cb + (size_t)cid * 32 * 1024 + col;
    float s = 0.f;
    #pragma unroll 8
    for (int r = 0; r < 32; ++r) s += p[(size_t)r * 1024];
    csum[cid * 1024 + col] = s;
}

__global__ __launch_bounds__(256) void scanp_kernel(const float* __restrict__ Cb,
                                                    const float* __restrict__ csum,
                                                    float* __restrict__ Pb)
{
    const int cid = blockIdx.x >> 2;
    const int col = ((blockIdx.x & 3) << 8) + threadIdx.x;
    float run = 0.f;
    for (int c = 0; c < cid; ++c) run += csum[c * 1024 + col];
    const float* p = Cb + (size_t)cid * 32 * 1024 + col;
    float* q = Pb + (size_t)cid * 32 * 1024 + col;
    for (int r = 0; r < 32; ++r) {
        q[(size_t)r * 1024] = run;
        run += p[(size_t)r * 1024];
    }
    if (cid == 31) Pb[(size_t)1024 * 1024 + col] = run;
}

// ============== build A = [q, q*PE], B = [k*(scale-PS), k] per head =======
__global__ __launch_bounds__(256) void ab_kernel(
    const float* __restrict__ Qb, const float* __restrict__ KVb,
    const float* __restrict__ Pb, const int* __restrict__ cwp,
    float* __restrict__ Ab, float* __restrict__ Bb)
{
    const int gid = blockIdx.x * 256 + threadIdx.x;
    const int i = gid >> 10;
    const int col = gid & 1023;
    const int h = col >> 6, dd = col & 63;
    const int cw = *cwp;
    const int E = min(i + cw, LQ);
    const int S = max(i - cw, 0);
    const float pe = Pb[(size_t)E * 1024 + col];
    const float ps = Pb[(size_t)S * 1024 + col];
    const float q = Qb[gid];
    const float k = KVb[(size_t)i * 2048 + col];
    const float scale = 0.125f;
    float* ap = Ab + ((size_t)(h * 1024 + i)) * 128;
    ap[dd] = q;
    ap[64 + dd] = q * pe;
    float* bp = Bb + ((size_t)(h * 1024 + i)) * 128;
    bp[dd] = k * (scale - ps);
    bp[64 + dd] = k;
}

// ===== V permute: Vt[h][j][dd] = KVb[j][1024 + h*64 + dd] =================
__global__ __launch_bounds__(256) void vcopy_kernel(const float* __restrict__ KVb,
                                                    float* __restrict__ Vt)
{
    const int h = blockIdx.y, j0 = blockIdx.x * 64;
    const int t = threadIdx.x;
    const int col = (t & 15) * 4;
    #pragma unroll
    for (int p = 0; p < 4; ++p) {
        int row = (t >> 4) + p * 16;
        float4 v = *(const float4*)(KVb + (size_t)(j0 + row) * 2048 + 1024 + h * 64 + col);
        *(float4*)(Vt + (size_t)(h * 1024 + j0 + row) * 64 + col) = v;
    }
}

// ======== flash attention: 32-row i-tiles, 128 thr, 512 balanced blocks ===
__global__ __launch_bounds__(128) void attn_kernel(
    const float* __restrict__ Ab, const float* __restrict__ Bt,
    const float* __restrict__ Vt, float* __restrict__ wv)
{
    __shared__ float As[32 * 132];     // [i][k] pad 132 (16896 B)
    __shared__ float Bs[128 * 64];     // [k][j] 32 KB; reused: Ps(64x36)+Vs(64x68)
    float* Ps = Bs;                    // [j][i] stride 36
    float* Vs = Bs + 64 * 36;          // [j][dd] stride 68
    const int t = threadIdx.x;
    const int tx = t & 15, ty = t >> 4;     // ty 0..7 -> i rows; tx -> j cols
    const int b = blockIdx.x;
    const int g = b >> 8, rr = b & 255;
    const int h = rr & 15;
    const int i32 = g ? (rr >> 4) : (31 - (rr >> 4));   // big tiles dispatch first
    const int i0 = i32 * 32;

    // stage A tile [i][k], coalesced loads, padded stride
    #pragma unroll
    for (int p = 0; p < 8; ++p) {
        int il = (t >> 5) + p * 4;
        int kf = (t & 31) * 4;
        float4 v = *(const float4*)(Ab + (size_t)(h * 1024 + i0 + il) * 128 + kf);
        *(float4*)&As[il * 132 + kf] = v;
    }

    float m[4], l[4], o[4][4];
    #pragma unroll
    for (int r = 0; r < 4; ++r) {
        m[r] = -1e30f; l[r] = 0.f;
        #pragma unroll
        for (int c = 0; c < 4; ++c) o[r][c] = 0.f;
    }

    const int njt = (i32 >> 1) + 1;
    for (int jt = 0; jt < njt; ++jt) {
        const int j0 = jt * 64;
        __syncthreads();   // prev PV reads done (Ps/Vs alias Bs); A-stage done
        #pragma unroll
        for (int p = 0; p < 16; ++p) {
            int k = (t >> 4) + p * 8;
            float4 v = *(const float4*)(Bt + (size_t)k * 16384 + h * 1024 + j0 + tx * 4);
            *(float4*)&Bs[k * 64 + tx * 4] = v;
        }
        __syncthreads();

        float s[4][4];
        #pragma unroll
        for (int r = 0; r < 4; ++r) { s[r][0]=0.f; s[r][1]=0.f; s[r][2]=0.f; s[r][3]=0.f; }
        for (int k4 = 0; k4 < 32; ++k4) {
            float aa[4][4], bb[4][4];
            #pragma unroll
            for (int r = 0; r < 4; ++r) {
                float4 v = *(const float4*)&As[(ty * 4 + r) * 132 + k4 * 4];
                aa[r][0] = v.x; aa[r][1] = v.y; aa[r][2] = v.z; aa[r][3] = v.w;
            }
            #pragma unroll
            for (int kk = 0; kk < 4; ++kk) {
                float4 v = *(const float4*)&Bs[(k4 * 4 + kk) * 64 + tx * 4];
                bb[kk][0] = v.x; bb[kk][1] = v.y; bb[kk][2] = v.z; bb[kk][3] = v.w;
            }
            #pragma unroll
            for (int kk = 0; kk < 4; ++kk)
                #pragma unroll
                for (int r = 0; r < 4; ++r)
                    #pragma unroll
                    for (int c = 0; c < 4; ++c)
                        s[r][c] = fmaf(aa[r][kk], bb[kk][c], s[r][c]);
        }
        if (jt == njt - 1) {  // diagonal tile: causal mask
            #pragma unroll
            for (int r = 0; r < 4; ++r)
                #pragma unroll
                for (int c = 0; c < 4; ++c)
                    if (j0 + tx * 4 + c > i0 + ty * 4 + r) s[r][c] = -1e30f;
        }

        float alpha[4];
        #pragma unroll
        for (int r = 0; r < 4; ++r) {
            float mt_ = fmaxf(fmaxf(s[r][0], s[r][1]), fmaxf(s[r][2], s[r][3]));
            mt_ = fmaxf(mt_, __shfl_xor(mt_, 1));
            mt_ = fmaxf(mt_, __shfl_xor(mt_, 2));
            mt_ = fmaxf(mt_, __shfl_xor(mt_, 4));
            mt_ = fmaxf(mt_, __shfl_xor(mt_, 8));
            const float mn = fmaxf(m[r], mt_);
            alpha[r] = __expf(m[r] - mn);
            m[r] = mn;
            float rs = 0.f;
            #pragma unroll
            for (int c = 0; c < 4; ++c) {
                float p = __expf(s[r][c] - mn);
                s[r][c] = p;
                rs += p;
            }
            rs += __shfl_xor(rs, 1); rs += __shfl_xor(rs, 2);
            rs += __shfl_xor(rs, 4); rs += __shfl_xor(rs, 8);
            l[r] = l[r] * alpha[r] + rs;
        }

        __syncthreads();   // done reading Bs
        #pragma unroll
        for (int c = 0; c < 4; ++c) {
            float4 pv;
            pv.x = s[0][c]; pv.y = s[1][c]; pv.z = s[2][c]; pv.w = s[3][c];
            *(float4*)&Ps[(tx * 4 + c) * 36 + ty * 4] = pv;
        }
        {
            const float* vb = Vt + (size_t)(h * 1024 + j0) * 64;
            #pragma unroll
            for (int p = 0; p < 8; ++p) {
                int f = p * 512 + t * 4;
                float4 v = *(const float4*)(vb + f);
                *(float4*)&Vs[(f >> 6) * 68 + (f & 63)] = v;
            }
        }
        __syncthreads();

        #pragma unroll
        for (int r = 0; r < 4; ++r)
            #pragma unroll
            for (int c = 0; c < 4; ++c) o[r][c] *= alpha[r];
        for (int j = 0; j < 64; ++j) {
            float4 pv = *(const float4*)&Ps[j * 36 + ty * 4];
            float4 vv = *(const float4*)&Vs[j * 68 + tx * 4];
            float pp[4] = {pv.x, pv.y, pv.z, pv.w};
            float vc[4] = {vv.x, vv.y, vv.z, vv.w};
            #pragma unroll
            for (int r = 0; r < 4; ++r)
                #pragma unroll
                for (int c = 0; c < 4; ++c)
                    o[r][c] = fmaf(pp[r], vc[c], o[r][c]);
        }
    }

    #pragma unroll
    for (int r = 0; r < 4; ++r) {
        const float inv = 1.0f / l[r];
        float4 ov;
        ov.x = o[r][0] * inv; ov.y = o[r][1] * inv;
        ov.z = o[r][2] * inv; ov.w = o[r][3] * inv;
        *(float4*)(wv + (size_t)(i0 + ty * 4 + r) * 1024 + h * 64 + tx * 4) = ov;
    }
}

// ================================ launch ==================================
extern "C" void kernel_launch(void* const* d_in, const int* in_sizes, int n_in,
                              void* d_out, int out_size, void* d_ws, size_t ws_size,
                              hipStream_t stream) {
    (void)in_sizes; (void)n_in; (void)out_size; (void)ws_size;
    const float* x    = (const float*)d_in[0];
    const float* pt   = (const float*)d_in[1];
    const float* gq   = (const float*)d_in[3];
    const float* Wq   = (const float*)d_in[4];
    const float* bq   = (const float*)d_in[5];
    const float* gkv  = (const float*)d_in[6];
    const float* Wkv  = (const float*)d_in[7];
    const float* bkv  = (const float*)d_in[8];
    const float* gc   = (const float*)d_in[9];
    const float* Wc   = (const float*)d_in[10];
    const float* bc   = (const float*)d_in[11];
    const float* Wout = (const float*)d_in[12];
    const float* bout = (const float*)d_in[13];
    const int*   cw   = (const int*)d_in[14];
    float* out = (float*)d_out;

    const size_t M1 = 1u << 20;
    float* ws   = (float*)d_ws;
    // slot reuse schedule (total 14*M1 floats = 56 MB, same as round 1):
    float* xqn  = ws + 0 * M1;   // dead after T -> Bb(0-1) -> wv? no: Bb here
    float* xkvn = ws + 1 * M1;
    float* ptn  = ws + 2 * M1;
    float* xqnT = ws + 3 * M1;   // dead after proj -> Bt(3-4)
    float* xkvnT= ws + 4 * M1;
    float* ptnT = ws + 5 * M1;   // dead after proj -> Vt(5)
    float* Qb   = ws + 6 * M1;   // dead after ab  -> wv(6)
    float* KVb  = ws + 7 * M1;   // 2M
    float* Cb   = ws + 9 * M1;   // dead after scanp -> wvT(9)
    float* Pb   = ws + 10 * M1;  // 1025*1024
    float* csum = ws + 11 * M1 + M1 / 2;  // 32K floats
    float* Ab   = ws + 12 * M1;  // 2M
    float* Bb   = ws + 0 * M1;   // over xqn/xkvn (dead)
    float* Bt   = ws + 3 * M1;   // over xqnT/xkvnT (dead)
    float* Vt   = ws + 5 * M1;   // over ptnT (dead)
    float* wvb  = ws + 6 * M1;   // over Qb (dead)
    float* wvT  = ws + 9 * M1;   // over Cb (dead)

    hipLaunchKernelGGL(rms_kernel, dim3(2048), dim3(256), 0, stream,
                       x, pt, gq, gkv, gc, xqn, xkvn, ptn);
    hipLaunchKernelGGL(transp_kernel, dim3(16, 16), dim3(256), 0, stream,
                       xqn, xqnT, 1024, 1024);
    hipLaunchKernelGGL(transp_kernel, dim3(16, 16), dim3(256), 0, stream,
                       xkvn, xkvnT, 1024, 1024);
    hipLaunchKernelGGL(transp_kernel, dim3(16, 16), dim3(256), 0, stream,
                       ptn, ptnT, 1024, 1024);
    hipLaunchKernelGGL(proj_kernel, dim3(512), dim3(128), 0, stream,
                       xqnT, xkvnT, ptnT, Wq, bq, Wkv, bkv, Wc, bc, Qb, KVb, Cb);
    hipLaunchKernelGGL(csum_kernel, dim3(128), dim3(256), 0, stream, Cb, csum);
    hipLaunchKernelGGL(scanp_kernel, dim3(128), dim3(256), 0, stream, Cb, csum, Pb);
    hipLaunchKernelGGL(ab_kernel, dim3(4096), dim3(256), 0, stream,
                       Qb, KVb, Pb, cw, Ab, Bb);
    hipLaunchKernelGGL(transp_kernel, dim3(2, 256), dim3(256), 0, stream,
                       Bb, Bt, 16384, 128);   // Bt[k][h*1024+j]
    hipLaunchKernelGGL(vcopy_kernel, dim3(16, 16), dim3(256), 0, stream, KVb, Vt);
    hipLaunchKernelGGL(attn_kernel, dim3(512), dim3(128), 0, stream,
                       Ab, Bt, Vt, wvb);
    hipLaunchKernelGGL(transp_kernel, dim3(16, 16), dim3(256), 0, stream,
                       wvb, wvT, 1024, 1024);
    hipLaunchKernelGGL(outgemm_kernel, dim3(16, 16), dim3(128), 0, stream,
                       wvT, Wout, bout, out);
}

// Round 3
// 246.191 us; speedup vs baseline: 2.1882x; 1.9988x over previous
//
#include <hip/hip_runtime.h>

#define LQ 1024
#define DM 1024

// ---------------------------------------------------------------------------
// Split-bf16 strategy: every value x is represented as hi=bf16(x),
// lo=bf16(x-hi); GEMMs run 3 MFMA passes (hh + hl + lh) giving ~2^-17
// relative precision — required because attention scores reach ~±100 and
// the softmax needs absolute score error << 1.
// ---------------------------------------------------------------------------

typedef __attribute__((ext_vector_type(8))) short bf16x8;   // 8 bf16 = 4 VGPR
typedef __attribute__((ext_vector_type(4))) float f32x4;    // MFMA 16x16 C/D

#define MFMA(a, b, c) __builtin_amdgcn_mfma_f32_16x16x32_bf16((a), (b), (c), 0, 0, 0)

__device__ __forceinline__ unsigned short f2bf(float x) {   // round-to-nearest-even
    unsigned int u = __float_as_uint(x);
    return (unsigned short)((u + 0x7FFFu + ((u >> 16) & 1u)) >> 16);
}
__device__ __forceinline__ float bf2f(unsigned short h) {
    return __uint_as_float(((unsigned int)h) << 16);
}
// async global->LDS, 16B per lane; LDS dest = wave-uniform base + lane*16 (m104)
__device__ __forceinline__ void gload16(const void* gp, void* lp) {
    __builtin_amdgcn_global_load_lds(
        (const __attribute__((address_space(1))) void*)gp,
        (__attribute__((address_space(3))) void*)lp, 16, 0, 0);
}
__device__ __forceinline__ void store_split4(unsigned short* ph, unsigned short* pl,
                                             float4 v) {
    unsigned short h0 = f2bf(v.x), h1 = f2bf(v.y), h2 = f2bf(v.z), h3 = f2bf(v.w);
    uint2 a;
    a.x = (unsigned)h0 | ((unsigned)h1 << 16);
    a.y = (unsigned)h2 | ((unsigned)h3 << 16);
    *(uint2*)ph = a;
    unsigned short l0 = f2bf(v.x - bf2f(h0)), l1 = f2bf(v.y - bf2f(h1));
    unsigned short l2 = f2bf(v.z - bf2f(h2)), l3 = f2bf(v.w - bf2f(h3));
    uint2 b;
    b.x = (unsigned)l0 | ((unsigned)l1 << 16);
    b.y = (unsigned)l2 | ((unsigned)l3 << 16);
    *(uint2*)pl = b;
}

// ============================ RMSNorm + split ==============================
__global__ __launch_bounds__(256) void rms_kernel(
    const float* __restrict__ x, const float* __restrict__ pt,
    const float* __restrict__ gq, const float* __restrict__ gkv,
    const float* __restrict__ gc,
    unsigned short* __restrict__ xqn_h, unsigned short* __restrict__ xqn_l,
    unsigned short* __restrict__ xkvn_h, unsigned short* __restrict__ xkvn_l,
    unsigned short* __restrict__ ptn_h, unsigned short* __restrict__ ptn_l)
{
    const int row = blockIdx.x;
    const int t = threadIdx.x;
    const bool isx = row < LQ;
    const float* src = isx ? (x + (size_t)row * DM)
                           : (pt + (size_t)(row - LQ) * DM);
    float4 v = ((const float4*)src)[t];
    float ss = v.x*v.x + v.y*v.y + v.z*v.z + v.w*v.w;
    #pragma unroll
    for (int o = 32; o > 0; o >>= 1) ss += __shfl_down(ss, o);
    __shared__ float red[4];
    if ((t & 63) == 0) red[t >> 6] = ss;
    __syncthreads();
    const float r = rsqrtf((red[0] + red[1] + red[2] + red[3]) * (1.0f / DM)
                           + 1.1920929e-07f);
    const size_t base = (size_t)(isx ? row : row - LQ) * DM + t * 4;
    if (isx) {
        float4 g1 = ((const float4*)gq)[t];
        float4 g2 = ((const float4*)gkv)[t];
        float4 y1, y2;
        y1.x = v.x*r*g1.x; y1.y = v.y*r*g1.y; y1.z = v.z*r*g1.z; y1.w = v.w*r*g1.w;
        y2.x = v.x*r*g2.x; y2.y = v.y*r*g2.y; y2.z = v.z*r*g2.z; y2.w = v.w*r*g2.w;
        store_split4(xqn_h + base, xqn_l + base, y1);
        store_split4(xkvn_h + base, xkvn_l + base, y2);
    } else {
        float4 g = ((const float4*)gc)[t];
        float4 y;
        y.x = v.x*r*g.x; y.y = v.y*r*g.y; y.z = v.z*r*g.z; y.w = v.w*r*g.w;
        store_split4(ptn_h + base, ptn_l + base, y);
    }
}

// ========== weight transpose + split: in[K][N] fp32 -> out[N][K] bf16 ======
__global__ __launch_bounds__(256) void wsplit_kernel(
    const float* __restrict__ in, unsigned short* __restrict__ oh,
    unsigned short* __restrict__ ol, int K, int N)
{
    __shared__ float T[64 * 65];
    const int t = threadIdx.x;
    const int tx = t & 15, ty = t >> 4;
    const int c0 = blockIdx.x * 64;   // n
    const int r0 = blockIdx.y * 64;   // k
    #pragma unroll
    for (int p = 0; p < 4; ++p) {
        int row = ty + p * 16;
        float4 v = *(const float4*)(in + (size_t)(r0 + row) * N + c0 + tx * 4);
        T[row * 65 + tx * 4 + 0] = v.x;
        T[row * 65 + tx * 4 + 1] = v.y;
        T[row * 65 + tx * 4 + 2] = v.z;
        T[row * 65 + tx * 4 + 3] = v.w;
    }
    __syncthreads();
    #pragma unroll
    for (int p = 0; p < 4; ++p) {
        int n = ty + p * 16;
        float4 w;
        w.x = T[(tx * 4 + 0) * 65 + n];
        w.y = T[(tx * 4 + 1) * 65 + n];
        w.z = T[(tx * 4 + 2) * 65 + n];
        w.w = T[(tx * 4 + 3) * 65 + n];
        size_t o = (size_t)(c0 + n) * K + r0 + tx * 4;
        store_split4(oh + o, ol + o, w);
    }
}

// ===== split-bf16 MFMA GEMM, 128x128 tile, 256 thr (4 waves 2x2) ===========
// A[h|l]: [1024][1024] bf16 row-major (M x K); B[h|l]: [N][1024] (i.e. W^T).
// BK=32 (64B LDS row stride -> 2-way banks = free; BK=64 would be 16-way).
__device__ __forceinline__ void gemm_mfma_128(
    const unsigned short* __restrict__ Ah, const unsigned short* __restrict__ Al,
    const unsigned short* __restrict__ Bh, const unsigned short* __restrict__ Bl,
    const float* __restrict__ bias, float* __restrict__ out, int N, int mt, int nt)
{
    __shared__ unsigned short sA[2][128 * 32];   // hi,lo  8KB each
    __shared__ unsigned short sB[2][128 * 32];
    const int t = threadIdx.x;
    const int lane = t & 63, wid = t >> 6;
    const int wm = wid >> 1, wn = wid & 1;
    const int n16 = lane & 15, quad = lane >> 4;
    f32x4 zero = {0.f, 0.f, 0.f, 0.f};
    f32x4 acc[4][4];
    #pragma unroll
    for (int ms = 0; ms < 4; ++ms)
        #pragma unroll
        for (int ns = 0; ns < 4; ++ns) acc[ms][ns] = zero;

    const int arow = wid * 16 + (lane >> 2);     // + p*64
    const int acol = (lane & 3) * 8;             // ushort offset within 32
    for (int kt = 0; kt < 32; ++kt) {
        const int k0 = kt * 32;
        #pragma unroll
        for (int p = 0; p < 2; ++p) {
            const int row = arow + p * 64;
            const size_t ga = (size_t)(mt * 128 + row) * 1024 + k0 + acol;
            const size_t gb = (size_t)(nt * 128 + row) * 1024 + k0 + acol;
            const int lo = p * 2048 + wid * 512;   // wave-uniform ushort offset
            gload16(Ah + ga, &sA[0][lo]);
            gload16(Al + ga, &sA[1][lo]);
            gload16(Bh + gb, &sB[0][lo]);
            gload16(Bl + gb, &sB[1][lo]);
        }
        __syncthreads();
        bf16x8 afh[4], afl[4], bfh[4], bfl[4];
        #pragma unroll
        for (int ms = 0; ms < 4; ++ms) {
            int r = wm * 64 + ms * 16 + n16;
            afh[ms] = *(const bf16x8*)&sA[0][r * 32 + quad * 8];
            afl[ms] = *(const bf16x8*)&sA[1][r * 32 + quad * 8];
        }
        #pragma unroll
        for (int ns = 0; ns < 4; ++ns) {
            int r = wn * 64 + ns * 16 + n16;
            bfh[ns] = *(const bf16x8*)&sB[0][r * 32 + quad * 8];
            bfl[ns] = *(const bf16x8*)&sB[1][r * 32 + quad * 8];
        }
        #pragma unroll
        for (int ms = 0; ms < 4; ++ms)
            #pragma unroll
            for (int ns = 0; ns < 4; ++ns) {
                acc[ms][ns] = MFMA(afh[ms], bfh[ns], acc[ms][ns]);
                acc[ms][ns] = MFMA(afh[ms], bfl[ns], acc[ms][ns]);
                acc[ms][ns] = MFMA(afl[ms], bfh[ns], acc[ms][ns]);
            }
        __syncthreads();
    }
    // epilogue: C/D layout col=lane&15, row=quad*4+reg (m89-verified)
    #pragma unroll
    for (int ns = 0; ns < 4; ++ns) {
        const int col = nt * 128 + wn * 64 + ns * 16 + n16;
        const float bv = bias[col];
        #pragma unroll
        for (int ms = 0; ms < 4; ++ms) {
            const int row0 = mt * 128 + wm * 64 + ms * 16 + quad * 4;
            #pragma unroll
            for (int reg = 0; reg < 4; ++reg)
                out[(size_t)(row0 + reg) * N + col] = acc[ms][ns][reg] + bv;
        }
    }
}

// Q(64 blocks) | KV(128) | C(64)
__global__ __launch_bounds__(256) void proj_kernel(
    const unsigned short* __restrict__ xqn_h, const unsigned short* __restrict__ xqn_l,
    const unsigned short* __restrict__ xkvn_h, const unsigned short* __restrict__ xkvn_l,
    const unsigned short* __restrict__ ptn_h, const unsigned short* __restrict__ ptn_l,
    const unsigned short* __restrict__ WqT_h, const unsigned short* __restrict__ WqT_l,
    const unsigned short* __restrict__ WkvT_h, const unsigned short* __restrict__ WkvT_l,
    const unsigned short* __restrict__ WcT_h, const unsigned short* __restrict__ WcT_l,
    const float* __restrict__ bq, const float* __restrict__ bkv,
    const float* __restrict__ bc,
    float* __restrict__ Qb, float* __restrict__ KVb, float* __restrict__ Cb)
{
    const int bid = blockIdx.x;
    if (bid < 64) {
        gemm_mfma_128(xqn_h, xqn_l, WqT_h, WqT_l, bq, Qb, 1024, bid >> 3, bid & 7);
    } else if (bid < 192) {
        int b2 = bid - 64;
        gemm_mfma_128(xkvn_h, xkvn_l, WkvT_h, WkvT_l, bkv, KVb, 2048, b2 >> 4, b2 & 15);
    } else {
        int b2 = bid - 192;
        gemm_mfma_128(ptn_h, ptn_l, WcT_h, WcT_l, bc, Cb, 1024, b2 >> 3, b2 & 7);
    }
}

// ===== out GEMM: 64x64 tile, 128 thr (2 waves), split-bf16 3-pass ==========
__global__ __launch_bounds__(128) void outgemm_kernel(
    const unsigned short* __restrict__ Ah, const unsigned short* __restrict__ Al,
    const unsigned short* __restrict__ Bh, const unsigned short* __restrict__ Bl,
    const float* __restrict__ bias, float* __restrict__ out)
{
    __shared__ unsigned short sA[2][64 * 32];
    __shared__ unsigned short sB[2][64 * 32];
    const int t = threadIdx.x;
    const int lane = t & 63, w = t >> 6;
    const int n16 = lane & 15, quad = lane >> 4;
    const int mt = blockIdx.y, nt = blockIdx.x;
    f32x4 zero = {0.f, 0.f, 0.f, 0.f};
    f32x4 acc[2][4];
    #pragma unroll
    for (int ms = 0; ms < 2; ++ms)
        #pragma unroll
        for (int ns = 0; ns < 4; ++ns) acc[ms][ns] = zero;

    const int arow = w * 16 + (lane >> 2);   // + p*32
    const int acol = (lane & 3) * 8;
    for (int kt = 0; kt < 32; ++kt) {
        const int k0 = kt * 32;
        #pragma unroll
        for (int p = 0; p < 2; ++p) {
            const int row = arow + p * 32;
            const size_t ga = (size_t)(mt * 64 + row) * 1024 + k0 + acol;
            const size_t gb = (size_t)(nt * 64 + row) * 1024 + k0 + acol;
            const int lo = p * 1024 + w * 512;
            gload16(Ah + ga, &sA[0][lo]);
            gload16(Al + ga, &sA[1][lo]);
            gload16(Bh + gb, &sB[0][lo]);
            gload16(Bl + gb, &sB[1][lo]);
        }
        __syncthreads();
        bf16x8 afh[2], afl[2], bfh[4], bfl[4];
        #pragma unroll
        for (int ms = 0; ms < 2; ++ms) {
            int r = w * 32 + ms * 16 + n16;
            afh[ms] = *(const bf16x8*)&sA[0][r * 32 + quad * 8];
            afl[ms] = *(const bf16x8*)&sA[1][r * 32 + quad * 8];
        }
        #pragma unroll
        for (int ns = 0; ns < 4; ++ns) {
            int r = ns * 16 + n16;
            bfh[ns] = *(const bf16x8*)&sB[0][r * 32 + quad * 8];
            bfl[ns] = *(const bf16x8*)&sB[1][r * 32 + quad * 8];
        }
        #pragma unroll
        for (int ms = 0; ms < 2; ++ms)
            #pragma unroll
            for (int ns = 0; ns < 4; ++ns) {
                acc[ms][ns] = MFMA(afh[ms], bfh[ns], acc[ms][ns]);
                acc[ms][ns] = MFMA(afh[ms], bfl[ns], acc[ms][ns]);
                acc[ms][ns] = MFMA(afl[ms], bfh[ns], acc[ms][ns]);
            }
        __syncthreads();
    }
    #pragma unroll
    for (int ns = 0; ns < 4; ++ns) {
        const int col = nt * 64 + ns * 16 + n16;
        const float bv = bias[col];
        #pragma unroll
        for (int ms = 0; ms < 2; ++ms) {
            const int row0 = mt * 64 + w * 32 + ms * 16 + quad * 4;
            #pragma unroll
            for (int reg = 0; reg < 4; ++reg)
                out[(size_t)(row0 + reg) * 1024 + col] = acc[ms][ns][reg] + bv;
        }
    }
}

// ================== prefix sums of C over rows (32-row chunks) =============
__global__ __launch_bounds__(256) void csum_kernel(const float* __restrict__ Cb,
                                                   float* __restrict__ csum)
{
    const int cid = blockIdx.x >> 2;
    const int col = ((blockIdx.x & 3) << 8) + threadIdx.x;
    const float* p = Cb + (size_t)cid * 32 * 1024 + col;
    float s = 0.f;
    #pragma unroll 8
    for (int r = 0; r < 32; ++r) s += p[(size_t)r * 1024];
    csum[cid * 1024 + col] = s;
}

__global__ __launch_bounds__(256) void scanp_kernel(const float* __restrict__ Cb,
                                                    const float* __restrict__ csum,
                                                    float* __restrict__ Pb)
{
    const int cid = blockIdx.x >> 2;
    const int col = ((blockIdx.x & 3) << 8) + threadIdx.x;
    float run = 0.f;
    for (int c = 0; c < cid; ++c) run += csum[c * 1024 + col];
    const float* p = Cb + (size_t)cid * 32 * 1024 + col;
    float* q = Pb + (size_t)cid * 32 * 1024 + col;
    for (int r = 0; r < 32; ++r) {
        q[(size_t)r * 1024] = run;
        run += p[(size_t)r * 1024];
    }
    if (cid == 31) Pb[(size_t)1024 * 1024 + col] = run;
}

// === build A=[q, q*PE], B=[k*(scale-PS), k] per head; split to bf16 hi/lo ==
__global__ __launch_bounds__(256) void ab_kernel(
    const float* __restrict__ Qb, const float* __restrict__ KVb,
    const float* __restrict__ Pb, const int* __restrict__ cwp,
    unsigned short* __restrict__ Aah, unsigned short* __restrict__ Aal,
    unsigned short* __restrict__ Bah, unsigned short* __restrict__ Bal)
{
    const int gid = blockIdx.x * 256 + threadIdx.x;
    const int i = gid >> 10;
    const int col = gid & 1023;
    const int h = col >> 6, dd = col & 63;
    const int cw = *cwp;
    const int E = min(i + cw, LQ);
    const int S = max(i - cw, 0);
    const float pe = Pb[(size_t)E * 1024 + col];
    const float ps = Pb[(size_t)S * 1024 + col];
    const float q = Qb[gid];
    const float k = KVb[(size_t)i * 2048 + col];
    const float scale = 0.125f;  // 64^-0.5
    const size_t base = ((size_t)(h * 1024 + i)) * 128;
    float a0 = q, a1 = q * pe;
    float b0 = k * (scale - ps), b1 = k;
    unsigned short hv;
    hv = f2bf(a0); Aah[base + dd] = hv;      Aal[base + dd] = f2bf(a0 - bf2f(hv));
    hv = f2bf(a1); Aah[base + 64 + dd] = hv; Aal[base + 64 + dd] = f2bf(a1 - bf2f(hv));
    hv = f2bf(b0); Bah[base + dd] = hv;      Bal[base + dd] = f2bf(b0 - bf2f(hv));
    hv = f2bf(b1); Bah[base + 64 + dd] = hv; Bal[base + 64 + dd] = f2bf(b1 - bf2f(hv));
}

// ===== V transpose to bf16: VT[h][d][j] = bf16(KVb[j][1024 + h*64 + d]) ====
__global__ __launch_bounds__(256) void vprep_kernel(const float* __restrict__ KVb,
                                                    unsigned short* __restrict__ VT)
{
    __shared__ float T[64 * 65];
    const int h = blockIdx.y, j0 = blockIdx.x * 64;
    const int t = threadIdx.x;
    const int tx = t & 15, ty = t >> 4;
    #pragma unroll
    for (int p = 0; p < 4; ++p) {
        int j = ty + p * 16;
        float4 v = *(const float4*)(KVb + (size_t)(j0 + j) * 2048 + 1024 + h * 64 + tx * 4);
        T[j * 65 + tx * 4 + 0] = v.x;
        T[j * 65 + tx * 4 + 1] = v.y;
        T[j * 65 + tx * 4 + 2] = v.z;
        T[j * 65 + tx * 4 + 3] = v.w;
    }
    __syncthreads();
    #pragma unroll
    for (int p = 0; p < 4; ++p) {
        int d = ty + p * 16;
        unsigned short e0 = f2bf(T[(tx * 4 + 0) * 65 + d]);
        unsigned short e1 = f2bf(T[(tx * 4 + 1) * 65 + d]);
        unsigned short e2 = f2bf(T[(tx * 4 + 2) * 65 + d]);
        unsigned short e3 = f2bf(T[(tx * 4 + 3) * 65 + d]);
        uint2 pk;
        pk.x = (unsigned)e0 | ((unsigned)e1 << 16);
        pk.y = (unsigned)e2 | ((unsigned)e3 << 16);
        *(uint2*)(VT + (size_t)(h * 64 + d) * 1024 + j0 + tx * 4) = pk;
    }
}

// ========== flash attention, MFMA split-bf16 scores, bf16 PV ===============
// 512 blocks (2/CU), 128 thr (2 waves), i-tile 32 (wave w owns 16 i-rows).
// A/B rows padded to 136 ushorts (272B = 17*16B: aligned, 2-way banks only).
__global__ __launch_bounds__(128) void attn_kernel(
    const unsigned short* __restrict__ Aah, const unsigned short* __restrict__ Aal,
    const unsigned short* __restrict__ Bah, const unsigned short* __restrict__ Bal,
    const unsigned short* __restrict__ VT,
    unsigned short* __restrict__ wvh, unsigned short* __restrict__ wvl)
{
    __shared__ unsigned short sA[2][32 * 136];   // 8704 B each (hi, lo)
    __shared__ unsigned short sB[2][64 * 136];   // 17408 B each
    unsigned short* Ps = sB[0];                  // [32][136] after S phase
    unsigned short* Vs = sB[0] + 32 * 136;       // [64][136] (spans into sB[1])

    const int t = threadIdx.x;
    const int lane = t & 63, w = t >> 6;
    const int n16 = lane & 15, quad = lane >> 4;
    const int b = blockIdx.x;
    const int g = b >> 8, rr = b & 255;
    const int h = rr & 15;
    const int it = g ? (rr >> 4) : (31 - (rr >> 4));   // big tiles dispatched first
    const int i0 = it * 32;
    const int njt = (it >> 1) + 1;

    {   // stage A hi/lo once: [32][128] -> padded rows
        const int r = t >> 2;
        const int cb = (t & 3) * 32;
        const unsigned short* gh = Aah + ((size_t)(h * 1024 + i0 + r)) * 128 + cb;
        const unsigned short* gl = Aal + ((size_t)(h * 1024 + i0 + r)) * 128 + cb;
        #pragma unroll
        for (int u = 0; u < 4; ++u) {
            *(uint4*)&sA[0][r * 136 + cb + u * 8] = *(const uint4*)(gh + u * 8);
            *(uint4*)&sA[1][r * 136 + cb + u * 8] = *(const uint4*)(gl + u * 8);
        }
    }

    f32x4 zero = {0.f, 0.f, 0.f, 0.f};
    f32x4 oacc[4];
    #pragma unroll
    for (int dt = 0; dt < 4; ++dt) oacc[dt] = zero;
    float mrow[4], lrow[4];
    #pragma unroll
    for (int reg = 0; reg < 4; ++reg) { mrow[reg] = -1e30f; lrow[reg] = 0.f; }

    for (int jt64 = 0; jt64 < njt; ++jt64) {
        const int j0 = jt64 * 64;
        __syncthreads();  // prev PV done with Ps/Vs (alias sB); A-stage done (iter 0)
        {   // stage B hi/lo: [64][128]
            const int r = t >> 1;
            const int cb = (t & 1) * 64;
            const unsigned short* gh = Bah + ((size_t)(h * 1024 + j0 + r)) * 128 + cb;
            const unsigned short* gl = Bal + ((size_t)(h * 1024 + j0 + r)) * 128 + cb;
            #pragma unroll
            for (int u = 0; u < 8; ++u) {
                *(uint4*)&sB[0][r * 136 + cb + u * 8] = *(const uint4*)(gh + u * 8);
                *(uint4*)&sB[1][r * 136 + cb + u * 8] = *(const uint4*)(gl + u * 8);
            }
        }
        __syncthreads();

        // S = A*B, 3-pass split (K=128 -> 4 chunks of 32)
        bf16x8 afh[4], afl[4];
        #pragma unroll
        for (int kc = 0; kc < 4; ++kc) {
            int r = w * 16 + n16;
            afh[kc] = *(const bf16x8*)&sA[0][r * 136 + kc * 32 + quad * 8];
            afl[kc] = *(const bf16x8*)&sA[1][r * 136 + kc * 32 + quad * 8];
        }
        f32x4 s[4];
        #pragma unroll
        for (int jt = 0; jt < 4; ++jt) s[jt] = zero;
        #pragma unroll
        for (int jt = 0; jt < 4; ++jt) {
            #pragma unroll
            for (int kc = 0; kc < 4; ++kc) {
                int r = jt * 16 + n16;
                bf16x8 bh = *(const bf16x8*)&sB[0][r * 136 + kc * 32 + quad * 8];
                bf16x8 bl = *(const bf16x8*)&sB[1][r * 136 + kc * 32 + quad * 8];
                s[jt] = MFMA(afh[kc], bh, s[jt]);
                s[jt] = MFMA(afh[kc], bl, s[jt]);
                s[jt] = MFMA(afl[kc], bh, s[jt]);
            }
        }
        if (jt64 == njt - 1) {   // causal mask on diagonal tile
            const int ibase = i0 + w * 16 + quad * 4;
            #pragma unroll
            for (int jt = 0; jt < 4; ++jt) {
                const int j = j0 + jt * 16 + n16;
                #pragma unroll
                for (int reg = 0; reg < 4; ++reg)
                    if (j > ibase + reg) s[jt][reg] = -1e30f;
            }
        }

        // online softmax; row = quad*4+reg, reduce over n (xor 1,2,4,8)
        float alpha[4];
        #pragma unroll
        for (int reg = 0; reg < 4; ++reg) {
            float mt_ = fmaxf(fmaxf(s[0][reg], s[1][reg]), fmaxf(s[2][reg], s[3][reg]));
            mt_ = fmaxf(mt_, __shfl_xor(mt_, 1));
            mt_ = fmaxf(mt_, __shfl_xor(mt_, 2));
            mt_ = fmaxf(mt_, __shfl_xor(mt_, 4));
            mt_ = fmaxf(mt_, __shfl_xor(mt_, 8));
            const float mn = fmaxf(mrow[reg], mt_);
            alpha[reg] = __expf(mrow[reg] - mn);
            mrow[reg] = mn;
            float rs = 0.f;
            #pragma unroll
            for (int jt = 0; jt < 4; ++jt) {
                float p = __expf(s[jt][reg] - mn);
                s[jt][reg] = p;
                rs += p;
            }
            rs += __shfl_xor(rs, 1); rs += __shfl_xor(rs, 2);
            rs += __shfl_xor(rs, 4); rs += __shfl_xor(rs, 8);
            lrow[reg] = lrow[reg] * alpha[reg] + rs;
        }

        __syncthreads();   // all waves done reading sB -> safe to overwrite with Ps/Vs
        // P (C-layout) -> LDS in A-operand layout [i][j] bf16
        #pragma unroll
        for (int jt = 0; jt < 4; ++jt)
            #pragma unroll
            for (int reg = 0; reg < 4; ++reg)
                Ps[(w * 16 + quad * 4 + reg) * 136 + jt * 16 + n16] = f2bf(s[jt][reg]);
        {   // stage V tile: Vs[d][j] from VT[h][d][1024]
            const int r = t >> 1;
            const int cb = (t & 1) * 32;
            const unsigned short* gv = VT + ((size_t)(h * 64 + r)) * 1024 + j0 + cb;
            #pragma unroll
            for (int u = 0; u < 4; ++u)
                *(uint4*)&Vs[r * 136 + cb + u * 8] = *(const uint4*)(gv + u * 8);
        }
        __syncthreads();

        // PV: o[dt] = alpha*o[dt] + P*V  (single-pass bf16; P in [0,1])
        #pragma unroll
        for (int dt = 0; dt < 4; ++dt)
            #pragma unroll
            for (int reg = 0; reg < 4; ++reg)
                oacc[dt][reg] *= alpha[reg];
        bf16x8 pf[2];
        #pragma unroll
        for (int kc = 0; kc < 2; ++kc)
            pf[kc] = *(const bf16x8*)&Ps[(w * 16 + n16) * 136 + kc * 32 + quad * 8];
        #pragma unroll
        for (int dt = 0; dt < 4; ++dt)
            #pragma unroll
            for (int kc = 0; kc < 2; ++kc) {
                bf16x8 vf = *(const bf16x8*)&Vs[(dt * 16 + n16) * 136 + kc * 32 + quad * 8];
                oacc[dt] = MFMA(pf[kc], vf, oacc[dt]);
            }
    }

    // epilogue: normalize, split to bf16 hi/lo, store wv[i][h*64+d]
    float inv[4];
    #pragma unroll
    for (int reg = 0; reg < 4; ++reg) inv[reg] = 1.0f / lrow[reg];
    #pragma unroll
    for (int dt = 0; dt < 4; ++dt) {
        #pragma unroll
        for (int reg = 0; reg < 4; ++reg) {
            const float v = oacc[dt][reg] * inv[reg];
            const size_t idx = (size_t)(i0 + w * 16 + quad * 4 + reg) * 1024
                             + h * 64 + dt * 16 + n16;
            const unsigned short hv = f2bf(v);
            wvh[idx] = hv;
            wvl[idx] = f2bf(v - bf2f(hv));
        }
    }
}

// ================================ launch ===================================
extern "C" void kernel_launch(void* const* d_in, const int* in_sizes, int n_in,
                              void* d_out, int out_size, void* d_ws, size_t ws_size,
                              hipStream_t stream) {
    (void)in_sizes; (void)n_in; (void)out_size; (void)ws_size;
    const float* x    = (const float*)d_in[0];
    const float* pt   = (const float*)d_in[1];
    const float* gq   = (const float*)d_in[3];
    const float* Wq   = (const float*)d_in[4];
    const float* bq   = (const float*)d_in[5];
    const float* gkv  = (const float*)d_in[6];
    const float* Wkv  = (const float*)d_in[7];
    const float* bkv  = (const float*)d_in[8];
    const float* gc   = (const float*)d_in[9];
    const float* Wc   = (const float*)d_in[10];
    const float* bc   = (const float*)d_in[11];
    const float* Wout = (const float*)d_in[12];
    const float* bout = (const float*)d_in[13];
    const int*   cw   = (const int*)d_in[14];
    float* out = (float*)d_out;

    char* W = (char*)d_ws;
    const size_t MB = 1u << 20;
    #define US(off) ((unsigned short*)(W + (off)))
    #define FP(off) ((float*)(W + (off)))
    // prep pool (dead after proj) 0..32MB:
    unsigned short* xqn_h  = US(0 * MB);
    unsigned short* xqn_l  = US(2 * MB);
    unsigned short* xkvn_h = US(4 * MB);
    unsigned short* xkvn_l = US(6 * MB);
    unsigned short* ptn_h  = US(8 * MB);
    unsigned short* ptn_l  = US(10 * MB);
    unsigned short* WqT_h  = US(12 * MB);
    unsigned short* WqT_l  = US(14 * MB);
    unsigned short* WkvT_h = US(16 * MB);
    unsigned short* WkvT_l = US(20 * MB);
    unsigned short* WcT_h  = US(24 * MB);
    unsigned short* WcT_l  = US(26 * MB);
    unsigned short* WoutT_h = US(28 * MB);   // live till end
    unsigned short* WoutT_l = US(30 * MB);
    float* Qb   = FP(32 * MB);   // 4 MB
    float* KVb  = FP(36 * MB);   // 8 MB
    float* Cb   = FP(44 * MB);   // 4 MB
    float* Pb   = FP(48 * MB);   // 4.004 MB (1025 rows)
    float* csum = FP(53 * MB);   // 128 KB
    // reuse of dead prep pool:
    unsigned short* Aah = US(0 * MB);    // 4 MB each
    unsigned short* Aal = US(4 * MB);
    unsigned short* Bah = US(8 * MB);
    unsigned short* Bal = US(12 * MB);
    unsigned short* VTb = US(16 * MB);   // 2 MB
    unsigned short* wv_h = US(18 * MB);  // 2 MB
    unsigned short* wv_l = US(20 * MB);  // 2 MB
    #undef US
    #undef FP

    hipLaunchKernelGGL(rms_kernel, dim3(2048), dim3(256), 0, stream,
                       x, pt, gq, gkv, gc, xqn_h, xqn_l, xkvn_h, xkvn_l, ptn_h, ptn_l);
    hipLaunchKernelGGL(wsplit_kernel, dim3(16, 16), dim3(256), 0, stream,
                       Wq, WqT_h, WqT_l, 1024, 1024);
    hipLaunchKernelGGL(wsplit_kernel, dim3(32, 16), dim3(256), 0, stream,
                       Wkv, WkvT_h, WkvT_l, 1024, 2048);
    hipLaunchKernelGGL(wsplit_kernel, dim3(16, 16), dim3(256), 0, stream,
                       Wc, WcT_h, WcT_l, 1024, 1024);
    hipLaunchKernelGGL(wsplit_kernel, dim3(16, 16), dim3(256), 0, stream,
                       Wout, WoutT_h, WoutT_l, 1024, 1024);
    hipLaunchKernelGGL(proj_kernel, dim3(256), dim3(256), 0, stream,
                       xqn_h, xqn_l, xkvn_h, xkvn_l, ptn_h, ptn_l,
                       WqT_h, WqT_l, WkvT_h, WkvT_l, WcT_h, WcT_l,
                       bq, bkv, bc, Qb, KVb, Cb);
    hipLaunchKernelGGL(csum_kernel, dim3(128), dim3(256), 0, stream, Cb, csum);
    hipLaunchKernelGGL(scanp_kernel, dim3(128), dim3(256), 0, stream, Cb, csum, Pb);
    hipLaunchKernelGGL(ab_kernel, dim3(4096), dim3(256), 0, stream,
                       Qb, KVb, Pb, cw, Aah, Aal, Bah, Bal);
    hipLaunchKernelGGL(vprep_kernel, dim3(16, 16), dim3(256), 0, stream, KVb, VTb);
    hipLaunchKernelGGL(attn_kernel, dim3(512), dim3(128), 0, stream,
                       Aah, Aal, Bah, Bal, VTb, wv_h, wv_l);
    hipLaunchKernelGGL(outgemm_kernel, dim3(16, 16), dim3(128), 0, stream,
                       wv_h, wv_l, WoutT_h, WoutT_l, bout, out);
}